// Round 6
// baseline (209.010 us; speedup 1.0000x reference)
//
#include <hip/hip_runtime.h>
#include <math.h>

// MoE router: logits = x[16384,2048] @ W^T[2048,64]; softmax; top-2; renorm.
//
// R11 post-mortem (router 78.8us, VGPR=56, Mfma 6.2%, everything idle):
// backedge trick held the x prefetch (32 VGPR) but LLVM still sank all 32
// W-loads/iter to their uses -> ~8 spare VGPRs -> ZERO MLP on W: serialized
// ~300-600cyc L2/L3 latency per load. Warm FETCH=4.5MB (x is L3-resident):
// the kernel is pure latency, no BW limit anywhere.
//
// R12 hybrid: W must be latency-decoupled WITHOUT VGPRs -> global_load_lds
// (VGPR-free DMA) into a double-buffered LDS tile, pre-ordered by w_split3 so
// the linear DMA lands in EXACT fragment order (ds_read_b128 of 64
// consecutive granules = dense, conflict-free, no swizzle). x stays
// fragment-direct in registers with depth-1 backedge prefetch (R11-proven).
// Counted-vmcnt barrier per step: vmcnt(2) retires the 4 W-DMAs, keeps the
// 2 x-loads in flight (R8 lesson: __syncthreads' vmcnt(0) would re-expose
// fresh x latency every step).
//
// Per-iteration vm ledger (per wave, order pinned by one sched_barrier):
//   1. stage_w(t+1) -> buf[(t+1)&1]      (4 DMA ops, oldest)
//   2. load x(t+1)  -> regs              (2 loads, youngest)
//   3. compute(t): split8(x regs) + 8 ds_read_b128 + 12 MFMA
//      (compiler emits vmcnt(6) for the x(t) regs -> DMA/x(t+1) untouched)
//   4. s_waitcnt vmcnt(2) lgkmcnt(0)     (W DMAs retired; ds ops drained)
//   5. s_barrier
// WAR: stage_w(t+1) overwrites the buffer ds_read in iter t-1; covered by
// iter t-1's step-4 lgkmcnt(0)+barrier. RAW: compute(t) reads buf staged in
// iter t-1, retired by its step-4 vmcnt(2).
//
// Decomposition: block = 256 thr = 4 waves = (tg,kh); 32 tok x 64 exp;
// wave = 16 tok (tg) x 64 exp x k32-half (kh) per k64 step; 32 steps.
// Grid 512 = 2 blocks/CU (launch_bounds(256,2)); LDS 32KB tiles + 8.5KB lg.
// fp16 split-precision MFMA (verified R5-R11, absmax 0.002): x=xh+xl,
// W=wh+wl, logits = xh*wh + xl*wh + xh*wl, fp32 acc.
//
// img granule g = step*1024 + ((kh*2+hl)*4+nt)*64 + L : lane L=(c,q) holds
// (hl?lo:hi) fp16 of W[nt*16+c][step*64 + kh*32 + q*8 .. +8].

typedef _Float16 half8  __attribute__((ext_vector_type(8)));
typedef float    floatx4 __attribute__((ext_vector_type(4)));

#define NTOK  16384
#define DDIM  2048
#define NE    64
#define TPB   32
#define NSTEP 32

__device__ inline void split8(const float4& a, const float4& b,
                              half8& hi, half8& lo) {
    float f[8] = {a.x, a.y, a.z, a.w, b.x, b.y, b.z, b.w};
#pragma unroll
    for (int j = 0; j < 8; ++j) {
        const _Float16 h = (_Float16)f[j];
        hi[j] = h;
        lo[j] = (_Float16)(f[j] - (float)h);
    }
}

typedef const __attribute__((address_space(1))) unsigned int* as1_u32p;
typedef __attribute__((address_space(3))) unsigned int*       as3_u32p;

__device__ inline void gload_lds16(const void* g, void* l) {
    // 16B/lane DMA; LDS dst = wave-uniform base + lane*16 (linear); counts
    // against vmcnt. R9-proven calling convention.
    __builtin_amdgcn_global_load_lds((as1_u32p)g, (as3_u32p)l, 16, 0, 0);
}

// ---- kernel 1: pre-split W into DMA/fragment-ordered image (512 KB) ----
__global__ __launch_bounds__(256) void w_split3(const float* __restrict__ W,
                                                _Float16* __restrict__ img) {
    const int g  = blockIdx.x * 256 + threadIdx.x;  // granule idx 0..32767
    const int L  = g & 63;
    const int B  = g >> 6;
    const int nt = B & 3;
    const int hl = (B >> 2) & 1;
    const int kh = (B >> 3) & 1;
    const int st = B >> 4;           // k64 step 0..31
    const int c  = L & 15, q = L >> 4;
    const float* src = W + (size_t)(nt * 16 + c) * DDIM
                         + st * 64 + kh * 32 + q * 8;
    const float4 a = *(const float4*)(src);
    const float4 b = *(const float4*)(src + 4);
    half8 hi, lo;
    split8(a, b, hi, lo);
    *(half8*)(img + (size_t)g * 8) = hl ? lo : hi;
}

// ---- kernel 2: hybrid GEMM + softmax + top-2 ----
__global__ __launch_bounds__(256, 2) void router_mfma(
    const float* __restrict__ x,
    const _Float16* __restrict__ img,
    float* __restrict__ out)
{
    __shared__ __align__(16) _Float16 tiles[2 * 8192];  // 2 x 16KB W tiles
    __shared__ __align__(16) float lg[TPB * 68];        // 8.5KB logits slab

    const int tid = threadIdx.x;
    const int L   = tid & 63;
    const int wv  = __builtin_amdgcn_readfirstlane(tid >> 6);  // 0..3
    const int kh  = wv & 1;          // k32 half of each k64 step
    const int tg  = wv >> 1;         // token group of 16
    const int c   = L & 15, q = L >> 4;
    const int btok = blockIdx.x * TPB;

    // x: lane (c,q) streams row btok+tg*16+c, k = s*64 + kh*32 + q*8 .. +8
    const float* xp = x + (size_t)(btok + tg * 16 + c) * DDIM + kh * 32 + q * 8;

    // B-frag LDS offsets (half units): granule ((kh*2+hl)*4+nt)*64 + L
    int boff[4][2];
#pragma unroll
    for (int nt = 0; nt < 4; ++nt)
#pragma unroll
        for (int hl = 0; hl < 2; ++hl)
            boff[nt][hl] = (((kh * 2 + hl) * 4 + nt) * 64 + L) * 8;

    floatx4 acc[4];
#pragma unroll
    for (int nt = 0; nt < 4; ++nt) acc[nt] = (floatx4)0.f;

    auto stage_w = [&](int sel, int t) {
        const char* src = (const char*)img + (size_t)t * 16384;
#pragma unroll
        for (int r = 0; r < 4; ++r) {
            const int gi0 = r * 256 + wv * 64;               // wave-uniform
            gload_lds16(src + (size_t)(gi0 + L) * 16,
                        &tiles[sel * 8192 + gi0 * 8]);
        }
    };

    auto compute = [&](int sel, const float4& xa, const float4& xb) {
        const _Float16* base = &tiles[sel * 8192];
        half8 Ah, Al;
        split8(xa, xb, Ah, Al);
#pragma unroll
        for (int nt = 0; nt < 4; ++nt) {
            const half8 Bh = *(const half8*)(base + boff[nt][0]);
            const half8 Bl = *(const half8*)(base + boff[nt][1]);
            acc[nt] = __builtin_amdgcn_mfma_f32_16x16x32_f16(Ah, Bh, acc[nt], 0, 0, 0);
            acc[nt] = __builtin_amdgcn_mfma_f32_16x16x32_f16(Al, Bh, acc[nt], 0, 0, 0);
            acc[nt] = __builtin_amdgcn_mfma_f32_16x16x32_f16(Ah, Bl, acc[nt], 0, 0, 0);
        }
    };

    // ---- prologue: W0 DMA (4) + x0 loads (2); vmcnt(2) keeps x0 in flight ----
    float4 pxa, pxb;
    {
        stage_w(0, 0);
        __builtin_amdgcn_sched_barrier(0);
        pxa = *(const float4*)(xp);
        pxb = *(const float4*)(xp + 4);
        asm volatile("s_waitcnt vmcnt(2) lgkmcnt(0)" ::: "memory");
        __builtin_amdgcn_s_barrier();
    }

    // ---- K loop: DMA W(t+1), prefetch x(t+1), compute t, counted barrier ----
    for (int t = 0; t < NSTEP - 1; ++t) {
        stage_w((t + 1) & 1, t + 1);                   // 4 DMA (oldest)
        __builtin_amdgcn_sched_barrier(0);
        const float4 nxa = *(const float4*)(xp + (t + 1) * 64);
        const float4 nxb = *(const float4*)(xp + (t + 1) * 64 + 4);
        compute(t & 1, pxa, pxb);    // compiler: vmcnt(6) for px, ds waits
        asm volatile("s_waitcnt vmcnt(2) lgkmcnt(0)" ::: "memory");
        __builtin_amdgcn_s_barrier();
        pxa = nxa; pxb = nxb;
    }
    compute((NSTEP - 1) & 1, pxa, pxb);
    __syncthreads();

    // ---- kh-pair reduction in lg (C/D: col=lane&15, row=(L>>4)*4+r) ----
    if (kh == 1) {
#pragma unroll
        for (int nt = 0; nt < 4; ++nt)
#pragma unroll
            for (int r = 0; r < 4; ++r)
                lg[(tg * 16 + q * 4 + r) * 68 + nt * 16 + c] = acc[nt][r];
    }
    __syncthreads();
    if (kh == 0) {
#pragma unroll
        for (int nt = 0; nt < 4; ++nt)
#pragma unroll
            for (int r = 0; r < 4; ++r) {
                const int o = (tg * 16 + q * 4 + r) * 68 + nt * 16 + c;
                lg[o] += acc[nt][r];
            }
    }
    __syncthreads();

    // ---- softmax + top-2: thread t < 32 owns token btok+t ----
    if (tid < TPB) {
        const int token = btok + tid;
        float* row = &lg[tid * 68];
        float pr[NE];
#pragma unroll
        for (int e = 0; e < NE; ++e) pr[e] = row[e];

        float m = pr[0];
#pragma unroll
        for (int e = 1; e < NE; ++e) m = fmaxf(m, pr[e]);
        float s = 0.f;
#pragma unroll
        for (int e = 0; e < NE; ++e) { pr[e] = expf(pr[e] - m); s += pr[e]; }
        const float inv = 1.f / s;

        // lax.top_k tie-break = lowest index first -> strict '>' ascending scan
        float v1 = -1.f; int i1 = 0;
#pragma unroll
        for (int e = 0; e < NE; ++e) { if (pr[e] > v1) { v1 = pr[e]; i1 = e; } }
        float v2 = -1.f; int i2 = 0;
#pragma unroll
        for (int e = 0; e < NE; ++e) { if (e != i1 && pr[e] > v2) { v2 = pr[e]; i2 = e; } }

        const float ts = v1 + v2;
        float* out_tp = out;              // top_k_probs  [NTOK][2]
        float* out_ti = out + 2 * NTOK;   // top_k_indices[NTOK][2] (float values)
        *(float2*)(out_tp + token * 2) = make_float2(v1 / ts, v2 / ts);
        *(float2*)(out_ti + token * 2) = make_float2((float)i1, (float)i2);

#pragma unroll
        for (int e = 0; e < NE; ++e) row[e] = pr[e] * inv;
    }
    __syncthreads();

    // ---- cooperative coalesced probs write: 32 tok x 64 = 2048 floats ----
    {
        float* out_p = out + 4 * NTOK + (size_t)btok * NE;
#pragma unroll
        for (int i = 0; i < 2; ++i) {
            const int f = tid + 256 * i;        // float4 idx, 512 total
            const int r = f >> 4, c4 = f & 15;
            const float4 v = *(const float4*)&lg[r * 68 + 4 * c4];
            *(float4*)(out_p + f * 4) = v;
        }
    }
}

extern "C" void kernel_launch(void* const* d_in, const int* in_sizes, int n_in,
                              void* d_out, int out_size, void* d_ws, size_t ws_size,
                              hipStream_t stream) {
    const float* x = (const float*)d_in[0];
    const float* W = (const float*)d_in[1];
    float* out     = (float*)d_out;
    _Float16* img  = (_Float16*)d_ws;   // 512 KB DMA-ordered W image

    w_split3<<<dim3(128), dim3(256), 0, stream>>>(W, img);
    router_mfma<<<dim3(NTOK / TPB), dim3(256), 0, stream>>>(x, img, out);
}

// Round 7
// 204.017 us; speedup vs baseline: 1.0245x; 1.0245x over previous
//
#include <hip/hip_runtime.h>
#include <math.h>

// MoE router: logits = x[16384,2048] @ W^T[2048,64]; softmax; top-2; renorm.
//
// R12 post-mortem: 4 schedules (dbuf/depth-2/counted-vmcnt/DMA-hybrid) all
// ~equal. Direct profiles (R10/R11): latency-bound, all pipes <12%, occupancy
// 21-44%. Invariants across the equal schedules: 8 waves/CU, W via a
// workspace image (cross-XCD written, post-fill cold), 2 kernels.
//
// R13: one kernel, no workspace, same traffic, 2x occupancy.
//  - W read directly as fp32 (read-only input -> XCD-local L2 after first
//    touch; 16KB fp32/step == img's 16KB fp16-pair: BYTES UNCHANGED), split
//    to fp16 hi/lo in registers during staging.
//  - Block 512thr = 8 waves = tg(2) x nh(4); wave = 16 tok x 16 exp x FULL K
//    (acc over all 32 k64 steps -> NO kh exchange). TPB=32, grid 512,
//    launch_bounds(512,4) -> 2 blocks/CU = 16 waves/CU = 4/SIMD (2x R12).
//  - T14 issue-early/write-late: next-tile loads issue before compute(t),
//    split+ds_write after; loads consumed BEFORE the single __syncthreads
//    per step, so its vmcnt(0) drain is free. No counted-vmcnt, no raw
//    barriers; one sched_barrier(0) pins load-issue above compute.
//
// fp16 split-precision MFMA (verified R5-R12, absmax 0.002): x=xh+xl,
// W=wh+wl, logits = xh*wh + xl*wh + xh*wl, fp32 acc.
//
// LDS per buffer (12288 halfs = 24KB): xh@0, xl@2048, wh@4096, wl@8192.
//  x tile 32tok x 64k, XOR-granule swizzle (R7-proven): granule g of row r
//    lives at slot g^(r&7); frag read banks balanced (8 lanes/bank-group =
//    b128 baseline).
//  W tile 64exp x 64k in fragment order: slot (ch*4+nt)*64+L holds
//    W[nt*16+(L&15)][step*64+ch*32+(L>>4)*8 ..+8] -> frag reads are 1024B
//    contiguous per wave (baseline), stage writes likewise contiguous.

typedef _Float16 half8  __attribute__((ext_vector_type(8)));
typedef _Float16 half4  __attribute__((ext_vector_type(4)));
typedef float    floatx4 __attribute__((ext_vector_type(4)));

#define NTOK  16384
#define DDIM  2048
#define NE    64
#define TPB   32
#define NSTEP 32

__device__ inline void split8(const float4& a, const float4& b,
                              half8& hi, half8& lo) {
    float f[8] = {a.x, a.y, a.z, a.w, b.x, b.y, b.z, b.w};
#pragma unroll
    for (int j = 0; j < 8; ++j) {
        const _Float16 h = (_Float16)f[j];
        hi[j] = h;
        lo[j] = (_Float16)(f[j] - (float)h);
    }
}

__device__ inline void split4(const float4& a, half4& hi, half4& lo) {
    float f[4] = {a.x, a.y, a.z, a.w};
#pragma unroll
    for (int j = 0; j < 4; ++j) {
        const _Float16 h = (_Float16)f[j];
        hi[j] = h;
        lo[j] = (_Float16)(f[j] - (float)h);
    }
}

__global__ __launch_bounds__(512, 4) void router_one(
    const float* __restrict__ x,
    const float* __restrict__ W,
    float* __restrict__ out)
{
    __shared__ __align__(16) _Float16 tiles[2 * 12288];  // 48KB double buffer
    __shared__ __align__(16) float lg[TPB * 68];         // 8.5KB logits slab

    const int tid = threadIdx.x;
    const int L   = tid & 63;
    const int wv  = __builtin_amdgcn_readfirstlane(tid >> 6);  // 0..7
    const int nh  = wv & 3;          // expert tile (16 experts)
    const int tg  = wv >> 2;         // token group (16 tokens)
    const int c   = L & 15, q = L >> 4;
    const int btok = blockIdx.x * TPB;

    // ---- staging maps ----
    // W: thread tid <-> (ch = tid>>8, nt = (tid>>6)&3, l = tid&63)
    const int su_ch = tid >> 8, su_nt = (tid >> 6) & 3, su_l = tid & 63;
    const float* wsrc = W + (size_t)(su_nt * 16 + (su_l & 15)) * DDIM
                          + su_ch * 32 + (su_l >> 4) * 8;
    const int w_off = tid * 8;       // half-elem offset in wh/wl regions

    // x: thread tid <-> (row sr = tid>>4, 4-float chunk hg = tid&15)
    const int sr = tid >> 4, hg = tid & 15;
    const float* xsrc = x + (size_t)(btok + sr) * DDIM + hg * 4;
    const int xg = hg >> 1, xh2 = hg & 1;
    const int xdst = (sr * 8 + (xg ^ (sr & 7))) * 8 + xh2 * 4;

    // ---- frag LDS offsets (half units) ----
    int aoff[2], boff[2];
#pragma unroll
    for (int ch = 0; ch < 2; ++ch) {
        aoff[ch] = ((tg * 16 + c) * 8 + ((ch * 4 + q) ^ (c & 7))) * 8;
        boff[ch] = ((ch * 4 + nh) * 64 + L) * 8;
    }

    floatx4 acc = (floatx4)0.f;

    auto stage = [&](int sel, const float4& wa, const float4& wb,
                     const float4& xa) {
        _Float16* nb = &tiles[sel * 12288];
        half8 whi, wlo; split8(wa, wb, whi, wlo);
        *(half8*)(nb + 4096 + w_off) = whi;
        *(half8*)(nb + 8192 + w_off) = wlo;
        half4 xhi, xlo; split4(xa, xhi, xlo);
        *(half4*)(nb + xdst)        = xhi;
        *(half4*)(nb + 2048 + xdst) = xlo;
    };

    auto compute = [&](int sel) {
        const _Float16* base = &tiles[sel * 12288];
#pragma unroll
        for (int ch = 0; ch < 2; ++ch) {
            const half8 Ah = *(const half8*)(base + aoff[ch]);
            const half8 Al = *(const half8*)(base + 2048 + aoff[ch]);
            const half8 Bh = *(const half8*)(base + 4096 + boff[ch]);
            const half8 Bl = *(const half8*)(base + 8192 + boff[ch]);
            acc = __builtin_amdgcn_mfma_f32_16x16x32_f16(Ah, Bh, acc, 0, 0, 0);
            acc = __builtin_amdgcn_mfma_f32_16x16x32_f16(Al, Bh, acc, 0, 0, 0);
            acc = __builtin_amdgcn_mfma_f32_16x16x32_f16(Ah, Bl, acc, 0, 0, 0);
        }
    };

    // ---- prologue: stage tile 0 ----
    {
        const float4 wa = *(const float4*)(wsrc);
        const float4 wb = *(const float4*)(wsrc + 4);
        const float4 xa = *(const float4*)(xsrc);
        stage(0, wa, wb, xa);
    }
    __syncthreads();

    // ---- K loop: issue t+1 loads early, compute t, split+write t+1 late ----
    for (int t = 0; t < NSTEP; ++t) {
        float4 wa, wb, xa;
        if (t + 1 < NSTEP) {
            wa = *(const float4*)(wsrc + (t + 1) * 64);
            wb = *(const float4*)(wsrc + (t + 1) * 64 + 4);
            xa = *(const float4*)(xsrc + (t + 1) * 64);
        }
        __builtin_amdgcn_sched_barrier(0);   // keep load-issue above compute
        compute(t & 1);
        if (t + 1 < NSTEP) stage((t + 1) & 1, wa, wb, xa);
        __syncthreads();   // loads consumed above -> vmcnt already drained
    }

    // ---- scatter: wave (tg,nh) owns its 16x16 tile; full K in acc ----
    // C/D: col(expert)=lane&15, row(token)=(L>>4)*4+r  (R5-R12 verified)
#pragma unroll
    for (int r = 0; r < 4; ++r)
        lg[(tg * 16 + q * 4 + r) * 68 + nh * 16 + c] = acc[r];
    __syncthreads();

    // ---- softmax + top-2: thread t < 32 owns token btok+t ----
    if (tid < TPB) {
        const int token = btok + tid;
        float* row = &lg[tid * 68];
        float pr[NE];
#pragma unroll
        for (int e = 0; e < NE; ++e) pr[e] = row[e];

        float m = pr[0];
#pragma unroll
        for (int e = 1; e < NE; ++e) m = fmaxf(m, pr[e]);
        float s = 0.f;
#pragma unroll
        for (int e = 0; e < NE; ++e) { pr[e] = expf(pr[e] - m); s += pr[e]; }
        const float inv = 1.f / s;

        // lax.top_k tie-break = lowest index first -> strict '>' ascending scan
        float v1 = -1.f; int i1 = 0;
#pragma unroll
        for (int e = 0; e < NE; ++e) { if (pr[e] > v1) { v1 = pr[e]; i1 = e; } }
        float v2 = -1.f; int i2 = 0;
#pragma unroll
        for (int e = 0; e < NE; ++e) { if (e != i1 && pr[e] > v2) { v2 = pr[e]; i2 = e; } }

        const float ts = v1 + v2;
        float* out_tp = out;              // top_k_probs  [NTOK][2]
        float* out_ti = out + 2 * NTOK;   // top_k_indices[NTOK][2] (float values)
        *(float2*)(out_tp + token * 2) = make_float2(v1 / ts, v2 / ts);
        *(float2*)(out_ti + token * 2) = make_float2((float)i1, (float)i2);

#pragma unroll
        for (int e = 0; e < NE; ++e) row[e] = pr[e] * inv;
    }
    __syncthreads();

    // ---- cooperative coalesced probs write: 32 tok x 64 = 2048 floats ----
    {
        float* out_p = out + 4 * NTOK + (size_t)btok * NE;
        const int r = tid >> 4, c4 = tid & 15;      // 512 float4s
        const float4 v = *(const float4*)&lg[r * 68 + 4 * c4];
        *(float4*)(out_p + tid * 4) = v;
    }
}

extern "C" void kernel_launch(void* const* d_in, const int* in_sizes, int n_in,
                              void* d_out, int out_size, void* d_ws, size_t ws_size,
                              hipStream_t stream) {
    const float* x = (const float*)d_in[0];
    const float* W = (const float*)d_in[1];
    float* out     = (float*)d_out;
    (void)d_ws; (void)ws_size;   // workspace unused: W split in-kernel

    router_one<<<dim3(NTOK / TPB), dim3(512), 0, stream>>>(x, W, out);
}